// Round 1
// baseline (854.825 us; speedup 1.0000x reference)
//
#include <hip/hip_runtime.h>

#define NB 16
#define NN 1024
#define MAXN 128
#define NU 8
#define NH 12
#define NMLP 16
#define KC 16
#define NCHUNK (NN / KC)  // 64

// ---------------------------------------------------------------------------
// Kernel 1: scan adjacency rows -> compacted neighbor index lists + deg
// one wave (64 threads) per (b,i) row; order within row irrelevant (sums).
// ---------------------------------------------------------------------------
__global__ __launch_bounds__(64) void k_build_idx(
    const float* __restrict__ adj, int* __restrict__ idxl,
    int* __restrict__ cnt, float* __restrict__ deg) {
  const int row = blockIdx.x;           // b*NN + i
  const int lane = threadIdx.x;
  const float4* arow = (const float4*)(adj + (size_t)row * NN);
  const unsigned long long ltmask = (1ull << lane) - 1ull;
  int base = 0;
  for (int rep = 0; rep < 4; ++rep) {
    float4 v = arow[rep * 64 + lane];
    float c[4] = {v.x, v.y, v.z, v.w};
#pragma unroll
    for (int cc = 0; cc < 4; ++cc) {
      bool nz = (c[cc] != 0.0f);
      unsigned long long m = __ballot(nz);
      if (nz) {
        int p = base + __popcll(m & ltmask);
        if (p < MAXN) idxl[(size_t)row * MAXN + p] = rep * 256 + lane * 4 + cc;
      }
      base += __popcll(m);
    }
  }
  if (lane == 0) {
    cnt[row] = base < MAXN ? base : MAXN;
    deg[row] = (float)base;
  }
}

// ---------------------------------------------------------------------------
// Kernel 2: per (b, k-chunk of 16 H-rows): stage 64KB of H in LDS.
//  - accumulate yh/hh partials (atomics)
//  - accumulate eg[b,i] = sum_{j in N(i)} sum_k H[k,i]H[k,j] partials (atomics)
// H is read from HBM exactly once across the whole grid.
// ---------------------------------------------------------------------------
__global__ __launch_bounds__(256) void k_eg(
    const float* __restrict__ H, const float* __restrict__ y,
    const int* __restrict__ idxl, const int* __restrict__ cnt,
    float* __restrict__ eg, float* __restrict__ yh, float* __restrict__ hh) {
  __shared__ float hs[KC][NN];  // 64 KB
  const int b = blockIdx.x >> 6;       // NCHUNK = 64
  const int chunk = blockIdx.x & 63;
  const int k0 = chunk * KC;
  const float* Hb = H + ((size_t)b * NN + k0) * NN;  // 16 contiguous rows

  // contiguous 64KB copy, vectorized
  const float4* src = (const float4*)Hb;
  float4* dst = (float4*)&hs[0][0];
  for (int t = threadIdx.x; t < KC * NN / 4; t += 256) dst[t] = src[t];
  __syncthreads();

  // yh / hh partials for this chunk
  float yv[KC];
#pragma unroll
  for (int k = 0; k < KC; ++k) yv[k] = y[b * NN + k0 + k];
  for (int j = threadIdx.x; j < NN; j += 256) {
    float py = 0.f, ph = 0.f;
#pragma unroll
    for (int k = 0; k < KC; ++k) {
      float h = hs[k][j];
      py += yv[k] * h;
      ph += h * h;
    }
    atomicAdd(&yh[b * NN + j], py);
    atomicAdd(&hh[b * NN + j], ph);
  }

  // eg partials: wave per i, lane owns one neighbor j, loops over k
  const int wave = threadIdx.x >> 6, lane = threadIdx.x & 63;
  for (int i = wave; i < NN; i += 4) {
    const int nnz = cnt[b * NN + i];
    float hi[KC];
#pragma unroll
    for (int k = 0; k < KC; ++k) hi[k] = hs[k][i];  // wave-uniform -> broadcast
    float acc = 0.f;
    for (int t = lane; t < nnz; t += 64) {
      int j = idxl[((size_t)b * NN + i) * MAXN + t];
      float a = 0.f;
#pragma unroll
      for (int k = 0; k < KC; ++k) a += hi[k] * hs[k][j];
      acc += a;
    }
#pragma unroll
    for (int off = 32; off; off >>= 1) acc += __shfl_down(acc, off, 64);
    if (lane == 0) atomicAdd(&eg[b * NN + i], acc);
  }
}

// ---------------------------------------------------------------------------
// Kernel 3: u0 = [yh, hh] @ W1^T + W1_b + b1
// ---------------------------------------------------------------------------
__global__ __launch_bounds__(256) void k_u0(
    const float* __restrict__ yh, const float* __restrict__ hh,
    const float* __restrict__ W1w, const float* __restrict__ W1b,
    const float* __restrict__ b1, float* __restrict__ u) {
  const int t = blockIdx.x * 256 + threadIdx.x;  // b*NN + j
  const float a = yh[t], c = hh[t];
#pragma unroll
  for (int o = 0; o < NU; ++o)
    u[(size_t)t * NU + o] = a * W1w[2 * o] + c * W1w[2 * o + 1] + W1b[o] + b1[o];
}

// ---------------------------------------------------------------------------
// Kernel 4: msum[b,i,:] = sum_{j in N(i)} u[b,j,:]   (wave per node)
// lane = (jgroup<<3) | comp ; 8 j's in flight x 8 components
// ---------------------------------------------------------------------------
__global__ __launch_bounds__(256) void k_gather(
    const float* __restrict__ u, const int* __restrict__ idxl,
    const int* __restrict__ cnt, float* __restrict__ msum) {
  const int wave = threadIdx.x >> 6, lane = threadIdx.x & 63;
  const int node = blockIdx.x * 4 + wave;  // b*NN + i
  const int nnz = cnt[node];
  const int c = lane & 7, g = lane >> 3;
  const int b = node >> 10;
  float acc = 0.f;
  for (int t = g; t < nnz; t += 8) {
    int j = idxl[(size_t)node * MAXN + t];
    acc += u[((size_t)(b << 10) + j) * NU + c];
  }
  acc += __shfl_xor(acc, 8, 64);
  acc += __shfl_xor(acc, 16, 64);
  acc += __shfl_xor(acc, 32, 64);
  if (lane < 8) msum[(size_t)node * NU + c] = acc;
}

// ---------------------------------------------------------------------------
// Kernel 5: fused msg-MLP + GRU + W2 (+ optional readout). thread per node.
// ---------------------------------------------------------------------------
__global__ __launch_bounds__(128) void k_update(
    const float* __restrict__ u_in, const float* __restrict__ msum,
    const float* __restrict__ deg, const float* __restrict__ eg,
    const float* __restrict__ rin, const float* __restrict__ nur,
    const float* __restrict__ Wm1w, const float* __restrict__ Wm1b,
    const float* __restrict__ Wm2w, const float* __restrict__ Wm2b,
    const float* __restrict__ gih, const float* __restrict__ ghh,
    const float* __restrict__ bih, const float* __restrict__ bhh,
    const float* __restrict__ W2w, const float* __restrict__ W2b,
    const float* __restrict__ b2,
    const float* __restrict__ Wr1w, const float* __restrict__ Wr1b,
    const float* __restrict__ Wr2w, const float* __restrict__ Wr2b,
    float* __restrict__ s, float* __restrict__ u_out, float* __restrict__ out,
    int first, int readout) {
  __shared__ float sWm1[NMLP * 3 * NU], sWm1b[NMLP], sWm2[NU * NMLP], sWm2b[NU];
  __shared__ float sgih[36 * (NU + 2)], sghh[36 * NH], sbih[36], sbhh[36];
  __shared__ float sW2[NU * NH], sW2b[NU], sb2[NU];
  __shared__ float sWr1[NMLP * NU], sWr1b[NMLP], sWr2[2 * NMLP], sWr2b[2];
  {
    auto cp = [&](float* d, const float* so, int n) {
      for (int t = threadIdx.x; t < n; t += 128) d[t] = so[t];
    };
    cp(sWm1, Wm1w, NMLP * 3 * NU); cp(sWm1b, Wm1b, NMLP);
    cp(sWm2, Wm2w, NU * NMLP);     cp(sWm2b, Wm2b, NU);
    cp(sgih, gih, 36 * (NU + 2));  cp(sghh, ghh, 36 * NH);
    cp(sbih, bih, 36);             cp(sbhh, bhh, 36);
    cp(sW2, W2w, NU * NH);         cp(sW2b, W2b, NU);   cp(sb2, b2, NU);
    cp(sWr1, Wr1w, NMLP * NU);     cp(sWr1b, Wr1b, NMLP);
    cp(sWr2, Wr2w, 2 * NMLP);      cp(sWr2b, Wr2b, 2);
  }
  __syncthreads();
  const int node = blockIdx.x * 128 + threadIdx.x;

  float agg[3 * NU];
  const float d = deg[node], e = eg[node];
#pragma unroll
  for (int o = 0; o < NU; ++o) {
    agg[o] = u_in[(size_t)node * NU + o] * d;
    agg[NU + o] = msum[(size_t)node * NU + o];
    agg[2 * NU + o] = e;
  }
  float h1[NMLP];
#pragma unroll
  for (int h = 0; h < NMLP; ++h) {
    float t = sWm1b[h];
#pragma unroll
    for (int i = 0; i < 3 * NU; ++i) t += sWm1[h * 3 * NU + i] * agg[i];
    h1[h] = fmaxf(t, 0.f);
  }
  float x[NU + 2];
#pragma unroll
  for (int o = 0; o < NU; ++o) {
    float t = sWm2b[o];
#pragma unroll
    for (int h = 0; h < NMLP; ++h) t += sWm2[o * NMLP + h] * h1[h];
    x[o] = t;
  }
  x[NU] = rin[node];
  x[NU + 1] = fmaxf(nur[node], 1e-10f);

  float sv[NH];
#pragma unroll
  for (int g = 0; g < NH; ++g) sv[g] = first ? 0.f : s[(size_t)node * NH + g];

  float sn[NH];
#pragma unroll
  for (int g = 0; g < NH; ++g) {
    float xr = sbih[g], xz = sbih[NH + g], xn = sbih[2 * NH + g];
#pragma unroll
    for (int i = 0; i < NU + 2; ++i) {
      xr += sgih[g * (NU + 2) + i] * x[i];
      xz += sgih[(NH + g) * (NU + 2) + i] * x[i];
      xn += sgih[(2 * NH + g) * (NU + 2) + i] * x[i];
    }
    float hr = sbhh[g], hz = sbhh[NH + g], hn = sbhh[2 * NH + g];
    if (!first) {
#pragma unroll
      for (int i = 0; i < NH; ++i) {
        hr += sghh[g * NH + i] * sv[i];
        hz += sghh[(NH + g) * NH + i] * sv[i];
        hn += sghh[(2 * NH + g) * NH + i] * sv[i];
      }
    }
    float rg = 1.f / (1.f + expf(-(xr + hr)));
    float zg = 1.f / (1.f + expf(-(xz + hz)));
    float ng = tanhf(xn + rg * hn);
    sn[g] = (1.f - zg) * ng + zg * sv[g];
  }
#pragma unroll
  for (int g = 0; g < NH; ++g) s[(size_t)node * NH + g] = sn[g];

  float un[NU];
#pragma unroll
  for (int o = 0; o < NU; ++o) {
    float t = sW2b[o] + sb2[o];
#pragma unroll
    for (int h = 0; h < NH; ++h) t += sW2[o * NH + h] * sn[h];
    un[o] = t;
    u_out[(size_t)node * NU + o] = t;
  }

  if (readout) {
    float h2[NMLP];
#pragma unroll
    for (int h = 0; h < NMLP; ++h) {
      float t = sWr1b[h];
#pragma unroll
      for (int o = 0; o < NU; ++o) t += sWr1[h * NU + o] * un[o];
      h2[h] = fmaxf(t, 0.f);
    }
    float l0 = sWr2b[0], l1 = sWr2b[1];
#pragma unroll
    for (int h = 0; h < NMLP; ++h) {
      l0 += sWr2[h] * h2[h];
      l1 += sWr2[NMLP + h] * h2[h];
    }
    float mx = fmaxf(l0, l1);
    float e0 = expf(l0 - mx), e1 = expf(l1 - mx);
    float inv = 1.f / (e0 + e1);
    float p0 = e0 * inv, p1 = e1 * inv;
    const float q0 = -0.70710678118654752f, q1 = 0.70710678118654752f;
    float xh = p0 * q0 + p1 * q1;
    float nu = p0 * (q0 - xh) * (q0 - xh) + p1 * (q1 - xh) * (q1 - xh);
    out[node] = xh;
    out[NB * NN + node] = fmaxf(nu, 1e-10f);
  }
}

// ---------------------------------------------------------------------------
extern "C" void kernel_launch(void* const* d_in, const int* in_sizes, int n_in,
                              void* d_out, int out_size, void* d_ws,
                              size_t ws_size, hipStream_t stream) {
  const float* y    = (const float*)d_in[0];
  const float* H    = (const float*)d_in[1];
  const float* r    = (const float*)d_in[2];
  const float* nur  = (const float*)d_in[3];
  const float* adj  = (const float*)d_in[4];
  const float* W1w  = (const float*)d_in[5];
  const float* W1b  = (const float*)d_in[6];
  const float* b1   = (const float*)d_in[7];
  const float* Wm1w = (const float*)d_in[8];
  const float* Wm1b = (const float*)d_in[9];
  const float* Wm2w = (const float*)d_in[10];
  const float* Wm2b = (const float*)d_in[11];
  const float* gih  = (const float*)d_in[12];
  const float* ghh  = (const float*)d_in[13];
  const float* bih  = (const float*)d_in[14];
  const float* bhh  = (const float*)d_in[15];
  const float* W2w  = (const float*)d_in[16];
  const float* W2b  = (const float*)d_in[17];
  const float* b2   = (const float*)d_in[18];
  const float* Wr1w = (const float*)d_in[19];
  const float* Wr1b = (const float*)d_in[20];
  const float* Wr2w = (const float*)d_in[21];
  const float* Wr2b = (const float*)d_in[22];
  float* out = (float*)d_out;

  // workspace carve (all 256B aligned)
  char* p = (char*)d_ws;
  auto carve = [&](size_t bytes) {
    void* q = (void*)p;
    p += (bytes + 255) & ~(size_t)255;
    return q;
  };
  int*   idxl = (int*)  carve((size_t)NB * NN * MAXN * 4);  // 8 MB
  int*   cnt  = (int*)  carve((size_t)NB * NN * 4);
  float* deg  = (float*)carve((size_t)NB * NN * 4);
  float* eg   = (float*)carve((size_t)NB * NN * 4);  // eg|yh|hh contiguous
  float* yh   = (float*)carve((size_t)NB * NN * 4);
  float* hh   = (float*)carve((size_t)NB * NN * 4);
  float* u    = (float*)carve((size_t)NB * NN * NU * 4);
  float* s    = (float*)carve((size_t)NB * NN * NH * 4);
  float* msum = (float*)carve((size_t)NB * NN * NU * 4);

  // zero the atomic accumulators (eg, yh, hh are contiguous carves of 64KB)
  hipMemsetAsync(eg, 0, 3 * ((size_t)NB * NN * 4 + 255 & ~(size_t)255), stream);

  k_build_idx<<<NB * NN, 64, 0, stream>>>(adj, idxl, cnt, deg);
  k_eg<<<NB * NCHUNK, 256, 0, stream>>>(H, y, idxl, cnt, eg, yh, hh);
  k_u0<<<NB * NN / 256, 256, 0, stream>>>(yh, hh, W1w, W1b, b1, u);

  for (int it = 0; it < 2; ++it) {
    k_gather<<<NB * NN / 4, 256, 0, stream>>>(u, idxl, cnt, msum);
    k_update<<<NB * NN / 128, 128, 0, stream>>>(
        u, msum, deg, eg, r, nur, Wm1w, Wm1b, Wm2w, Wm2b, gih, ghh, bih, bhh,
        W2w, W2b, b2, Wr1w, Wr1b, Wr2w, Wr2b, s, u, out,
        /*first=*/it == 0, /*readout=*/it == 1);
  }
}

// Round 3
// 416.340 us; speedup vs baseline: 2.0532x; 2.0532x over previous
//
#include <hip/hip_runtime.h>

#define NB 16
#define NN 1024
#define NBN (NB * NN)
#define MAXN 128
#define NU 8
#define NH 12
#define NMLP 16
#define KC 16
#define NCHUNK (NN / KC)  // 64

// swizzled float4-quadrant slot within hsT: row j (16 floats), quadrant c
// keeps 16B alignment; spreads random-j b128 reads over all 8 bank classes
#define QSW(j, c) (((j) << 4) + ((((c) ^ (((j) >> 2) & 3)) & 3) << 2))

// ---------------------------------------------------------------------------
// Kernel 1: scan adjacency rows -> transposed neighbor lists idxT[t][row]
// (uint16), cnt, deg; also zeroes the fp32 atomic accumulators eg/yh/hh.
// one wave per row, 4 rows per block.
// ---------------------------------------------------------------------------
__global__ __launch_bounds__(256) void k_build_idx(
    const float* __restrict__ adj, unsigned short* __restrict__ idxT,
    int* __restrict__ cnt, float* __restrict__ deg,
    float* __restrict__ eg, float* __restrict__ yh, float* __restrict__ hh) {
  const int row = blockIdx.x * 4 + (threadIdx.x >> 6);
  const int lane = threadIdx.x & 63;
  const float4* arow = (const float4*)(adj + (size_t)row * NN);
  float4 v[4];
#pragma unroll
  for (int rep = 0; rep < 4; ++rep) v[rep] = arow[rep * 64 + lane];  // ILP
  const unsigned long long ltmask = (1ull << lane) - 1ull;
  int base = 0;
#pragma unroll
  for (int rep = 0; rep < 4; ++rep) {
    float c[4] = {v[rep].x, v[rep].y, v[rep].z, v[rep].w};
#pragma unroll
    for (int cc = 0; cc < 4; ++cc) {
      bool nz = (c[cc] != 0.0f);
      unsigned long long m = __ballot(nz);
      if (nz) {
        int p = base + __popcll(m & ltmask);
        if (p < MAXN)
          idxT[(size_t)p * NBN + row] = (unsigned short)(rep * 256 + lane * 4 + cc);
      }
      base += __popcll(m);
    }
  }
  if (lane == 0) {
    cnt[row] = base < MAXN ? base : MAXN;
    deg[row] = (float)base;
    eg[row] = 0.f; yh[row] = 0.f; hh[row] = 0.f;
  }
}

// ---------------------------------------------------------------------------
// Kernel 2: per (b, chunk of 16 H-rows): stage transposed+swizzled in LDS.
//  - yh/hh partials (conflict-free b128 row reads, atomics)
//  - eg partials, lane-owns-i: hi in registers, per neighbor 4x ds_read_b128
// ---------------------------------------------------------------------------
__global__ __launch_bounds__(512) void k_eg(
    const float* __restrict__ H, const float* __restrict__ y,
    const unsigned short* __restrict__ idxT, const int* __restrict__ cnt,
    float* __restrict__ eg, float* __restrict__ yh, float* __restrict__ hh) {
  __shared__ float hsT[NN * KC];  // 64 KB
  const int b = blockIdx.x >> 6;
  const int k0 = (blockIdx.x & 63) * KC;
  const int tid = threadIdx.x;
  const float* Hb = H + ((size_t)b * NN + k0) * NN;

  // stage transposed: 16 coalesced scalar loads -> 4 b128 LDS writes per col
  for (int j0 = tid; j0 < NN; j0 += 512) {
    float hv[KC];
#pragma unroll
    for (int k = 0; k < KC; ++k) hv[k] = Hb[(size_t)k * NN + j0];
#pragma unroll
    for (int c = 0; c < 4; ++c)
      *(float4*)&hsT[QSW(j0, c)] = ((const float4*)hv)[c];
  }
  __syncthreads();

  // yh / hh partials
  {
    float yv[KC];
#pragma unroll
    for (int k = 0; k < KC; ++k) yv[k] = y[b * NN + k0 + k];
    for (int j = tid; j < NN; j += 512) {
      float hv[KC];
#pragma unroll
      for (int c = 0; c < 4; ++c)
        ((float4*)hv)[c] = *(const float4*)&hsT[QSW(j, c)];
      float py = 0.f, ph = 0.f;
#pragma unroll
      for (int k = 0; k < KC; ++k) { py += yv[k] * hv[k]; ph += hv[k] * hv[k]; }
      atomicAdd(&yh[b * NN + j], py);
      atomicAdd(&hh[b * NN + j], ph);
    }
  }

  // eg partials: lane owns i (consecutive i per lane -> coalesced idx reads)
  for (int rep = 0; rep < 2; ++rep) {
    const int i = rep * 512 + tid;
    const int node = b * NN + i;
    const int nnz = cnt[node];
    int mx = nnz;
#pragma unroll
    for (int off = 32; off; off >>= 1) mx = max(mx, __shfl_xor(mx, off, 64));
    float hi[KC];
#pragma unroll
    for (int c = 0; c < 4; ++c)
      ((float4*)hi)[c] = *(const float4*)&hsT[QSW(i, c)];
    float acc = 0.f;
    int jcur = (nnz > 0) ? (int)idxT[node] : 0;
    for (int t = 0; t < mx; ++t) {
      int jnext = (t + 1 < nnz) ? (int)idxT[(size_t)(t + 1) * NBN + node] : 0;
      if (t < nnz) {
        float hj[KC];
#pragma unroll
        for (int c = 0; c < 4; ++c)
          ((float4*)hj)[c] = *(const float4*)&hsT[QSW(jcur, c)];
        float a0 = 0.f, a1 = 0.f, a2 = 0.f, a3 = 0.f;
#pragma unroll
        for (int k = 0; k < 4; ++k) {
          a0 += hi[k] * hj[k];
          a1 += hi[4 + k] * hj[4 + k];
          a2 += hi[8 + k] * hj[8 + k];
          a3 += hi[12 + k] * hj[12 + k];
        }
        acc += (a0 + a1) + (a2 + a3);
      }
      jcur = jnext;
    }
    atomicAdd(&eg[node], acc);
  }
}

// ---------------------------------------------------------------------------
// Kernel 3: u0 = [yh, hh] @ W1^T + W1_b + b1
// ---------------------------------------------------------------------------
__global__ __launch_bounds__(256) void k_u0(
    const float* __restrict__ yh, const float* __restrict__ hh,
    const float* __restrict__ W1w, const float* __restrict__ W1b,
    const float* __restrict__ b1, float* __restrict__ u) {
  const int t = blockIdx.x * 256 + threadIdx.x;  // b*NN + j
  const float a = yh[t], c = hh[t];
#pragma unroll
  for (int o = 0; o < NU; ++o)
    u[(size_t)t * NU + o] = a * W1w[2 * o] + c * W1w[2 * o + 1] + W1b[o] + b1[o];
}

// ---------------------------------------------------------------------------
// Kernel 4: msum[node,:] = sum_{j in N(node)} u[b,j,:]  (lane owns node)
// ---------------------------------------------------------------------------
__global__ __launch_bounds__(256) void k_gather(
    const float* __restrict__ u, const unsigned short* __restrict__ idxT,
    const int* __restrict__ cnt, float* __restrict__ msum) {
  const int node = blockIdx.x * 256 + threadIdx.x;
  const int nnz = cnt[node];
  int mx = nnz;
#pragma unroll
  for (int off = 32; off; off >>= 1) mx = max(mx, __shfl_xor(mx, off, 64));
  const float* ub = u + (size_t)(node & ~(NN - 1)) * NU;  // batch base
  float4 acc0 = {0, 0, 0, 0}, acc1 = {0, 0, 0, 0};
  for (int t = 0; t < mx; ++t) {
    if (t < nnz) {
      int j = idxT[(size_t)t * NBN + node];
      const float4* up = (const float4*)(ub + (size_t)j * NU);
      float4 a = up[0], b4 = up[1];
      acc0.x += a.x;  acc0.y += a.y;  acc0.z += a.z;  acc0.w += a.w;
      acc1.x += b4.x; acc1.y += b4.y; acc1.z += b4.z; acc1.w += b4.w;
    }
  }
  float4* mp = (float4*)&msum[(size_t)node * NU];
  mp[0] = acc0;
  mp[1] = acc1;
}

// ---------------------------------------------------------------------------
// Kernel 5: fused msg-MLP + GRU + W2 (+ optional readout). thread per node.
// ---------------------------------------------------------------------------
__global__ __launch_bounds__(128) void k_update(
    const float* __restrict__ u_in, const float* __restrict__ msum,
    const float* __restrict__ deg, const float* __restrict__ eg,
    const float* __restrict__ rin, const float* __restrict__ nur,
    const float* __restrict__ Wm1w, const float* __restrict__ Wm1b,
    const float* __restrict__ Wm2w, const float* __restrict__ Wm2b,
    const float* __restrict__ gih, const float* __restrict__ ghh,
    const float* __restrict__ bih, const float* __restrict__ bhh,
    const float* __restrict__ W2w, const float* __restrict__ W2b,
    const float* __restrict__ b2,
    const float* __restrict__ Wr1w, const float* __restrict__ Wr1b,
    const float* __restrict__ Wr2w, const float* __restrict__ Wr2b,
    float* __restrict__ s, float* __restrict__ u_out, float* __restrict__ out,
    int first, int readout) {
  __shared__ float sWm1[NMLP * 3 * NU], sWm1b[NMLP], sWm2[NU * NMLP], sWm2b[NU];
  __shared__ float sgih[36 * (NU + 2)], sghh[36 * NH], sbih[36], sbhh[36];
  __shared__ float sW2[NU * NH], sW2b[NU], sb2[NU];
  __shared__ float sWr1[NMLP * NU], sWr1b[NMLP], sWr2[2 * NMLP], sWr2b[2];
  {
    auto cp = [&](float* d, const float* so, int n) {
      for (int t = threadIdx.x; t < n; t += 128) d[t] = so[t];
    };
    cp(sWm1, Wm1w, NMLP * 3 * NU); cp(sWm1b, Wm1b, NMLP);
    cp(sWm2, Wm2w, NU * NMLP);     cp(sWm2b, Wm2b, NU);
    cp(sgih, gih, 36 * (NU + 2));  cp(sghh, ghh, 36 * NH);
    cp(sbih, bih, 36);             cp(sbhh, bhh, 36);
    cp(sW2, W2w, NU * NH);         cp(sW2b, W2b, NU);   cp(sb2, b2, NU);
    cp(sWr1, Wr1w, NMLP * NU);     cp(sWr1b, Wr1b, NMLP);
    cp(sWr2, Wr2w, 2 * NMLP);      cp(sWr2b, Wr2b, 2);
  }
  __syncthreads();
  const int node = blockIdx.x * 128 + threadIdx.x;

  float agg[3 * NU];
  const float d = deg[node], e = eg[node];
#pragma unroll
  for (int o = 0; o < NU; ++o) {
    agg[o] = u_in[(size_t)node * NU + o] * d;
    agg[NU + o] = msum[(size_t)node * NU + o];
    agg[2 * NU + o] = e;
  }
  float h1[NMLP];
#pragma unroll
  for (int h = 0; h < NMLP; ++h) {
    float t = sWm1b[h];
#pragma unroll
    for (int i = 0; i < 3 * NU; ++i) t += sWm1[h * 3 * NU + i] * agg[i];
    h1[h] = fmaxf(t, 0.f);
  }
  float x[NU + 2];
#pragma unroll
  for (int o = 0; o < NU; ++o) {
    float t = sWm2b[o];
#pragma unroll
    for (int h = 0; h < NMLP; ++h) t += sWm2[o * NMLP + h] * h1[h];
    x[o] = t;
  }
  x[NU] = rin[node];
  x[NU + 1] = fmaxf(nur[node], 1e-10f);

  float sv[NH];
#pragma unroll
  for (int g = 0; g < NH; ++g) sv[g] = first ? 0.f : s[(size_t)node * NH + g];

  float sn[NH];
#pragma unroll
  for (int g = 0; g < NH; ++g) {
    float xr = sbih[g], xz = sbih[NH + g], xn = sbih[2 * NH + g];
#pragma unroll
    for (int i = 0; i < NU + 2; ++i) {
      xr += sgih[g * (NU + 2) + i] * x[i];
      xz += sgih[(NH + g) * (NU + 2) + i] * x[i];
      xn += sgih[(2 * NH + g) * (NU + 2) + i] * x[i];
    }
    float hr = sbhh[g], hz = sbhh[NH + g], hn = sbhh[2 * NH + g];
    if (!first) {
#pragma unroll
      for (int i = 0; i < NH; ++i) {
        hr += sghh[g * NH + i] * sv[i];
        hz += sghh[(NH + g) * NH + i] * sv[i];
        hn += sghh[(2 * NH + g) * NH + i] * sv[i];
      }
    }
    float rg = 1.f / (1.f + expf(-(xr + hr)));
    float zg = 1.f / (1.f + expf(-(xz + hz)));
    float ng = tanhf(xn + rg * hn);
    sn[g] = (1.f - zg) * ng + zg * sv[g];
  }
#pragma unroll
  for (int g = 0; g < NH; ++g) s[(size_t)node * NH + g] = sn[g];

  float un[NU];
#pragma unroll
  for (int o = 0; o < NU; ++o) {
    float t = sW2b[o] + sb2[o];
#pragma unroll
    for (int h = 0; h < NH; ++h) t += sW2[o * NH + h] * sn[h];
    un[o] = t;
    u_out[(size_t)node * NU + o] = t;
  }

  if (readout) {
    float h2[NMLP];
#pragma unroll
    for (int h = 0; h < NMLP; ++h) {
      float t = sWr1b[h];
#pragma unroll
      for (int o = 0; o < NU; ++o) t += sWr1[h * NU + o] * un[o];
      h2[h] = fmaxf(t, 0.f);
    }
    float l0 = sWr2b[0], l1 = sWr2b[1];
#pragma unroll
    for (int h = 0; h < NMLP; ++h) {
      l0 += sWr2[h] * h2[h];
      l1 += sWr2[NMLP + h] * h2[h];
    }
    float mx = fmaxf(l0, l1);
    float e0 = expf(l0 - mx), e1 = expf(l1 - mx);
    float inv = 1.f / (e0 + e1);
    float p0 = e0 * inv, p1 = e1 * inv;
    const float q0 = -0.70710678118654752f, q1 = 0.70710678118654752f;
    float xh = p0 * q0 + p1 * q1;
    float nu = p0 * (q0 - xh) * (q0 - xh) + p1 * (q1 - xh) * (q1 - xh);
    out[node] = xh;
    out[NB * NN + node] = fmaxf(nu, 1e-10f);
  }
}

// ---------------------------------------------------------------------------
extern "C" void kernel_launch(void* const* d_in, const int* in_sizes, int n_in,
                              void* d_out, int out_size, void* d_ws,
                              size_t ws_size, hipStream_t stream) {
  const float* y    = (const float*)d_in[0];
  const float* H    = (const float*)d_in[1];
  const float* r    = (const float*)d_in[2];
  const float* nur  = (const float*)d_in[3];
  const float* adj  = (const float*)d_in[4];
  const float* W1w  = (const float*)d_in[5];
  const float* W1b  = (const float*)d_in[6];
  const float* b1   = (const float*)d_in[7];
  const float* Wm1w = (const float*)d_in[8];
  const float* Wm1b = (const float*)d_in[9];
  const float* Wm2w = (const float*)d_in[10];
  const float* Wm2b = (const float*)d_in[11];
  const float* gih  = (const float*)d_in[12];
  const float* ghh  = (const float*)d_in[13];
  const float* bih  = (const float*)d_in[14];
  const float* bhh  = (const float*)d_in[15];
  const float* W2w  = (const float*)d_in[16];
  const float* W2b  = (const float*)d_in[17];
  const float* b2   = (const float*)d_in[18];
  const float* Wr1w = (const float*)d_in[19];
  const float* Wr1b = (const float*)d_in[20];
  const float* Wr2w = (const float*)d_in[21];
  const float* Wr2b = (const float*)d_in[22];
  float* out = (float*)d_out;

  // workspace carve (all 256B aligned)
  char* p = (char*)d_ws;
  auto carve = [&](size_t bytes) {
    void* q = (void*)p;
    p += (bytes + 255) & ~(size_t)255;
    return q;
  };
  unsigned short* idxT = (unsigned short*)carve((size_t)MAXN * NBN * 2);  // 4 MB
  int*   cnt  = (int*)  carve((size_t)NBN * 4);
  float* deg  = (float*)carve((size_t)NBN * 4);
  float* eg   = (float*)carve((size_t)NBN * 4);
  float* yh   = (float*)carve((size_t)NBN * 4);
  float* hh   = (float*)carve((size_t)NBN * 4);
  float* u    = (float*)carve((size_t)NBN * NU * 4);
  float* s    = (float*)carve((size_t)NBN * NH * 4);
  float* msum = (float*)carve((size_t)NBN * NU * 4);

  k_build_idx<<<NBN / 4, 256, 0, stream>>>(adj, idxT, cnt, deg, eg, yh, hh);
  k_eg<<<NB * NCHUNK, 512, 0, stream>>>(H, y, idxT, cnt, eg, yh, hh);
  k_u0<<<NBN / 256, 256, 0, stream>>>(yh, hh, W1w, W1b, b1, u);

  for (int it = 0; it < 2; ++it) {
    k_gather<<<NBN / 256, 256, 0, stream>>>(u, idxT, cnt, msum);
    k_update<<<NBN / 128, 128, 0, stream>>>(
        u, msum, deg, eg, r, nur, Wm1w, Wm1b, Wm2w, Wm2b, gih, ghh, bih, bhh,
        W2w, W2b, b2, Wr1w, Wr1b, Wr2w, Wr2b, s, u, out,
        /*first=*/it == 0, /*readout=*/it == 1);
  }
}